// Round 12
// baseline (552.050 us; speedup 1.0000x reference)
//
#include <hip/hip_runtime.h>
#include <hip/hip_bf16.h>
#include <math.h>

#define NTOK 16384
#define DDIM 1024
#define HALF 512
#define SUB  512
#define KDIM 512
#define TOPK 8
#define NCAND 16
#define VDIM 128
#define TMB 32          // tokens per block (score kernel)
#define GATE 1.2e-3f

typedef __attribute__((ext_vector_type(8))) _Float16 f16x8;
typedef __attribute__((ext_vector_type(4))) float f32x4;

static __device__ __forceinline__ int pk2(float a, float b) {
    _Float16 ha = (_Float16)a, hb = (_Float16)b;
    return (int)__builtin_bit_cast(unsigned short, ha)
         | ((int)__builtin_bit_cast(unsigned short, hb) << 16);
}
static __device__ __forceinline__ void splitpk(float a, float b, int& h, int& l) {
    _Float16 ha = (_Float16)a, hb = (_Float16)b;
    _Float16 la = (_Float16)(a - (float)ha), lb = (_Float16)(b - (float)hb);
    h = (int)__builtin_bit_cast(unsigned short, ha)
      | ((int)__builtin_bit_cast(unsigned short, hb) << 16);
    l = (int)__builtin_bit_cast(unsigned short, la)
      | ((int)__builtin_bit_cast(unsigned short, lb) << 16);
}

// ---------------------------------------------------------------------------
// Kernel 0: codebooks -> single-f16 MFMA-B fragments (layout as R9-R11).
//   slice = hf*4 + cq (cq = 128-cand group); step s = kstep*8 + nt(0..7).
//   frag elem: n = cq*128 + nt*16 + (lane&15), k = kstep*32 + (lane>>4)*8 + j.
// ---------------------------------------------------------------------------
__global__ __launch_bounds__(256)
void cvt_bfrag(const float* __restrict__ cb1, const float* __restrict__ cb2,
               char* __restrict__ Bp)
{
    int fid   = blockIdx.x * 256 + threadIdx.x;   // 0..65535
    int lane  = fid & 63;
    int s     = (fid >> 6) & 127;
    int slice = fid >> 13;
    int nt = s & 7, kstep = s >> 3;
    int cq = slice & 3, hf = slice >> 2;
    const float* cb = hf ? cb2 : cb1;
    int n = cq * 128 + nt * 16 + (lane & 15);
    int k = kstep * 32 + (lane >> 4) * 8;
    const float* src = cb + (size_t)n * KDIM + k;
    float4 f0 = *(const float4*)src;
    float4 f1 = *(const float4*)(src + 4);
    int4 v;
    v.x = pk2(f0.x, f0.y); v.y = pk2(f0.z, f0.w);
    v.z = pk2(f1.x, f1.y); v.w = pk2(f1.z, f1.w);
    *(int4*)(Bp + (size_t)fid * 16) = v;
}

// ---------------------------------------------------------------------------
// Kernel 1: fused score+topk. 512 threads (8 waves), 32 tokens, one half.
//   Wave = 64-cand slice (4 nt tiles) x 32 tokens (2 tok-tiles).
//   f16 2-term: s = qh*c + ql*c. A staged per K-half (32 KB LDS, overlaid by
//   sS[16][512] in phase 2). B: global->reg 4-slot ring, reload +1 kstep.
//   Phase 2: shuffle-free ballot-bisect (static bracket, gate via one extra
//   count), 2 tokens per wave interleaved; fp64 slow path (proven) for the
//   ~5% ambiguous tokens.
// ---------------------------------------------------------------------------
__global__ __launch_bounds__(512, 4)
void score_topk_fused(const float* __restrict__ query,
                      const float* __restrict__ cb1f,
                      const float* __restrict__ cb2f,
                      const char* __restrict__ Bp,
                      int*   __restrict__ tk_idx,
                      float* __restrict__ tk_val)
{
    __shared__ char smem[32768];
    // GEMM: A frags [seg(8)][tt(2)][hi/lo][lane*16B]; phase 2: sS[16][512]
    float* sS = (float*)smem;

    const int tid  = threadIdx.x;
    const int hf   = blockIdx.y;
    const int tok0 = blockIdx.x * TMB;
    const float* __restrict__ cbf = hf ? cb2f : cb1f;
    const int qoff = hf * HALF;

    const int lane = tid & 63;
    const int wid  = tid >> 6;          // 0..7 = 64-cand slice
    const int l15  = lane & 15;
    const int lh   = lane >> 4;

    // B slice pointer: cq = wid>>1; steps sg + nt, sg base (wid&1)*4
    const char* bp = Bp + (size_t)(hf * 4 + (wid >> 1)) * 131072 + lane * 16;
    const int ntb = (wid & 1) * 4;

    int4 ring[4];
    #pragma unroll
    for (int nt = 0; nt < 4; nt++)
        ring[nt] = *(const int4*)(bp + (ntb + nt) * 1024);

    f32x4 acc0[4], acc1[4];
    #pragma unroll
    for (int nt = 0; nt < 4; nt++) {
        acc0[nt] = (f32x4){0.f, 0.f, 0.f, 0.f};
        acc1[nt] = (f32x4){0.f, 0.f, 0.f, 0.f};
    }

    for (int h = 0; h < 2; h++) {
        // ---- stage A half h: 32 tok x 256 k -> qh/ql f16 fragments ----
        {
            const int tok = tid >> 4;        // 0..31
            const int s16 = tid & 15;        // 16-k segment
            const int tt  = tok >> 4;
            const int row = tok & 15;
            const float* src = query + (size_t)(tok0 + tok) * DDIM + qoff
                               + h * 256 + s16 * 16;
            char* base = smem + (s16 >> 1) * 4096 + tt * 2048;
            const int lw0 = row + 32 * (s16 & 1);   // frag lane of elems 0-7
            int4 vh0, vl0, vh1, vl1;
            {
                float4 f0 = *(const float4*)(src);
                float4 f1 = *(const float4*)(src + 4);
                splitpk(f0.x, f0.y, vh0.x, vl0.x);
                splitpk(f0.z, f0.w, vh0.y, vl0.y);
                splitpk(f1.x, f1.y, vh0.z, vl0.z);
                splitpk(f1.z, f1.w, vh0.w, vl0.w);
            }
            {
                float4 f2 = *(const float4*)(src + 8);
                float4 f3 = *(const float4*)(src + 12);
                splitpk(f2.x, f2.y, vh1.x, vl1.x);
                splitpk(f2.z, f2.w, vh1.y, vl1.y);
                splitpk(f3.x, f3.y, vh1.z, vl1.z);
                splitpk(f3.z, f3.w, vh1.w, vl1.w);
            }
            *(int4*)(base + lw0 * 16)               = vh0;
            *(int4*)(base + 1024 + lw0 * 16)        = vl0;
            *(int4*)(base + (lw0 + 16) * 16)        = vh1;
            *(int4*)(base + 1024 + (lw0 + 16) * 16) = vl1;
        }
        __syncthreads();

        for (int ks = 0; ks < 8; ks++) {
            const char* abase = smem + ks * 4096;
            f16x8 qh0 = *(const f16x8*)(abase + lane * 16);
            f16x8 ql0 = *(const f16x8*)(abase + 1024 + lane * 16);
            f16x8 qh1 = *(const f16x8*)(abase + 2048 + lane * 16);
            f16x8 ql1 = *(const f16x8*)(abase + 3072 + lane * 16);
            const int sg = (h * 8 + ks) * 8 + ntb;
            #pragma unroll
            for (int nt = 0; nt < 4; nt++) {
                f16x8 b = __builtin_bit_cast(f16x8, ring[nt]);
                ring[nt] = *(const int4*)(bp + ((sg + nt + 8) & 127) * 1024);
                acc0[nt] = __builtin_amdgcn_mfma_f32_16x16x32_f16(qh0, b, acc0[nt], 0, 0, 0);
                acc1[nt] = __builtin_amdgcn_mfma_f32_16x16x32_f16(qh1, b, acc1[nt], 0, 0, 0);
                acc0[nt] = __builtin_amdgcn_mfma_f32_16x16x32_f16(ql0, b, acc0[nt], 0, 0, 0);
                acc1[nt] = __builtin_amdgcn_mfma_f32_16x16x32_f16(ql1, b, acc1[nt], 0, 0, 0);
            }
        }
        __syncthreads();   // A(h) reads done before restage / sS overlay
    }

    // ---- phase 2 helpers (all LDS + scalars; no register arrays passed) ----
    auto slowpath = [&](int t, int tok) {
        const int hsh = ((t >> 2) & 3) << 3;
        float sv[8];
        #pragma unroll
        for (int j = 0; j < 8; j++) sv[j] = sS[t * SUB + ((lane + 64 * j) ^ hsh)];
        int cand[NCAND];
        #pragma unroll
        for (int r = 0; r < NCAND; r++) {
            float bv = sv[0]; int bj = 0;
            #pragma unroll
            for (int j = 1; j < 8; j++) if (sv[j] > bv) { bv = sv[j]; bj = j; }
            int bidx = lane + 64 * bj;
            #pragma unroll
            for (int off = 32; off > 0; off >>= 1) {
                float ov = __shfl_xor(bv, off);
                int   oi = __shfl_xor(bidx, off);
                if (ov > bv || (ov == bv && oi < bidx)) { bv = ov; bidx = oi; }
            }
            cand[r] = bidx;
            int jj = bidx >> 6;
            if ((bidx & 63) == lane) {
                #pragma unroll
                for (int j = 0; j < 8; j++) if (j == jj) sv[j] = -INFINITY;
            }
        }
        double qd[8];
        #pragma unroll
        for (int j = 0; j < 8; j++)
            qd[j] = (double)query[(size_t)tok * DDIM + qoff + lane + 64 * j];
        double rv[NCAND];
        #pragma unroll
        for (int r = 0; r < NCAND; r++) {
            const float* __restrict__ crow = &cbf[(size_t)cand[r] * KDIM];
            double a = 0.0;
            #pragma unroll
            for (int j = 0; j < 8; j++)
                a = fma(qd[j], (double)crow[lane + 64 * j], a);
            #pragma unroll
            for (int off = 32; off > 0; off >>= 1)
                a += __shfl_xor(a, off);
            rv[r] = a;
        }
        if (lane == 0) {
            #pragma unroll
            for (int r = 0; r < NCAND; r++) {
                int rk = 0;
                #pragma unroll
                for (int mm = 0; mm < NCAND; mm++)
                    if (rv[mm] > rv[r] || (rv[mm] == rv[r] && cand[mm] < cand[r])) rk++;
                if (rk < TOPK) {
                    tk_idx[((size_t)tok * 2 + hf) * TOPK + rk] = cand[r];
                    tk_val[((size_t)tok * 2 + hf) * TOPK + rk] = (float)rv[r];
                }
            }
        }
    };

    // two tokens per wave per round, bisects interleaved (2x ILP)
    auto topk_pair = [&](int rr) {
        const int tA   = wid * 2;
        const int tB   = wid * 2 + 1;
        const int tokA = tok0 + rr * 16 + tA;
        const int tokB = tok0 + rr * 16 + tB;
        const int hA   = ((tA >> 2) & 3) << 3;
        const int hB   = ((tB >> 2) & 3) << 3;

        float sa[8], sb[8];
        #pragma unroll
        for (int j = 0; j < 8; j++) {
            sa[j] = sS[tA * SUB + ((lane + 64 * j) ^ hA)];
            sb[j] = sS[tB * SUB + ((lane + 64 * j) ^ hB)];
        }
        auto cntA = [&](float tau) -> int {
            int c = 0;
            #pragma unroll
            for (int j = 0; j < 8; j++) c += __popcll(__ballot(sa[j] > tau));
            return c;
        };
        auto cntB = [&](float tau) -> int {
            int c = 0;
            #pragma unroll
            for (int j = 0; j < 8; j++) c += __popcll(__ballot(sb[j] > tau));
            return c;
        };

        float loA = 0.f, hiA = 2.f, loB = 0.f, hiB = 2.f;
        while (cntA(loA) < 9) loA -= 0.5f;     // ~never
        while (cntA(hiA) > 8) hiA += 1.f;      // ~never
        while (cntB(loB) < 9) loB -= 0.5f;
        while (cntB(hiB) > 8) hiB += 1.f;
        for (int it = 0; it < 16; it++) {
            float mA = 0.5f * (loA + hiA), mB = 0.5f * (loB + hiB);
            int cA = cntA(mA), cB = cntB(mB);
            if (cA >= 9) loA = mA; else hiA = mA;
            if (cB >= 9) loB = mB; else hiB = mB;
        }
        bool fastA = (cntA(hiA) == 8) && (cntA(hiA - GATE) == 8);
        bool fastB = (cntB(hiB) == 8) && (cntB(hiB - GATE) == 8);

        if (fastA) {
            int base = 0;
            #pragma unroll
            for (int j = 0; j < 8; j++) {
                unsigned long long mk = __ballot(sa[j] > hiA);
                if (sa[j] > hiA) {
                    int pos = base + __popcll(mk & ((1ULL << lane) - 1ULL));
                    tk_idx[((size_t)tokA * 2 + hf) * TOPK + pos] = lane + 64 * j;
                    tk_val[((size_t)tokA * 2 + hf) * TOPK + pos] = sa[j];
                }
                base += __popcll(mk);
            }
        }
        if (fastB) {
            int base = 0;
            #pragma unroll
            for (int j = 0; j < 8; j++) {
                unsigned long long mk = __ballot(sb[j] > hiB);
                if (sb[j] > hiB) {
                    int pos = base + __popcll(mk & ((1ULL << lane) - 1ULL));
                    tk_idx[((size_t)tokB * 2 + hf) * TOPK + pos] = lane + 64 * j;
                    tk_val[((size_t)tokB * 2 + hf) * TOPK + pos] = sb[j];
                }
                base += __popcll(mk);
            }
        }
        if (!fastA) slowpath(tA, tokA);
        if (!fastB) slowpath(tB, tokB);
    };

    // ---- round 0: dump acc0 (tokens 0-15), static indices ----
    #pragma unroll
    for (int nt = 0; nt < 4; nt++)
        #pragma unroll
        for (int r = 0; r < 4; r++) {
            int t = lh * 4 + r;
            int c = wid * 64 + nt * 16 + l15;
            sS[t * SUB + (c ^ (lh << 3))] = acc0[nt][r];
        }
    __syncthreads();
    topk_pair(0);
    __syncthreads();

    // ---- round 1: dump acc1 (tokens 16-31) ----
    #pragma unroll
    for (int nt = 0; nt < 4; nt++)
        #pragma unroll
        for (int r = 0; r < 4; r++) {
            int t = lh * 4 + r;
            int c = wid * 64 + nt * 16 + l15;
            sS[t * SUB + (c ^ (lh << 3))] = acc1[nt][r];
        }
    __syncthreads();
    topk_pair(1);
}

// ---------------------------------------------------------------------------
// Kernel 2: one wave per token. softmax(8)x2 -> 64 weighted value rows.
// (R6-proven float2 version, ~51 us)
// ---------------------------------------------------------------------------
__global__ __launch_bounds__(256)
void gather_kernel(const float* __restrict__ values,
                   const int*   __restrict__ tk_idx,
                   const float* __restrict__ tk_val,
                   float* __restrict__ out)
{
    const int tid  = threadIdx.x;
    const int lane = tid & 63;
    const int tok  = blockIdx.x * 4 + (tid >> 6);

    const int b1 = (tok * 2 + 0) * TOPK;
    const int b2 = (tok * 2 + 1) * TOPK;

    float v1[8], v2[8]; int i1[8], i2[8];
    #pragma unroll
    for (int j = 0; j < 8; j++) {
        i1[j] = tk_idx[b1 + j]; v1[j] = tk_val[b1 + j];
        i2[j] = tk_idx[b2 + j]; v2[j] = tk_val[b2 + j];
    }

    float m1 = v1[0], m2 = v2[0];
    #pragma unroll
    for (int j = 1; j < 8; j++) { m1 = fmaxf(m1, v1[j]); m2 = fmaxf(m2, v2[j]); }

    float w1[8], w2[8], s1 = 0.f, s2 = 0.f;
    #pragma unroll
    for (int j = 0; j < 8; j++) {
        w1[j] = expf(v1[j] - m1); s1 += w1[j];
        w2[j] = expf(v2[j] - m2); s2 += w2[j];
    }
    const float inv1 = 1.f / s1, inv2 = 1.f / s2;
    #pragma unroll
    for (int j = 0; j < 8; j++) { w1[j] *= inv1; w2[j] *= inv2; }

    float2 accA = make_float2(0.f, 0.f), accB = make_float2(0.f, 0.f);
    #pragma unroll
    for (int i = 0; i < 8; i++) {
        const int rb = i1[i] * SUB;
        const float wi = w1[i];
        #pragma unroll
        for (int j = 0; j < 8; j += 2) {
            const float wa = wi * w2[j];
            const float wb = wi * w2[j + 1];
            const float* __restrict__ ra  = values + (size_t)(rb + i2[j])     * VDIM;
            const float* __restrict__ rbp = values + (size_t)(rb + i2[j + 1]) * VDIM;
            float2 ta = *(const float2*)&ra[lane * 2];
            float2 tb = *(const float2*)&rbp[lane * 2];
            accA.x = fmaf(wa, ta.x, accA.x);
            accA.y = fmaf(wa, ta.y, accA.y);
            accB.x = fmaf(wb, tb.x, accB.x);
            accB.y = fmaf(wb, tb.y, accB.y);
        }
    }
    float2 acc = make_float2(accA.x + accB.x, accA.y + accB.y);
    *(float2*)&out[(size_t)tok * VDIM + lane * 2] = acc;
}

extern "C" void kernel_launch(void* const* d_in, const int* in_sizes, int n_in,
                              void* d_out, int out_size, void* d_ws, size_t ws_size,
                              hipStream_t stream) {
    const float* query  = (const float*)d_in[0];
    const float* cb1    = (const float*)d_in[1];
    const float* cb2    = (const float*)d_in[2];
    const float* values = (const float*)d_in[3];
    float* out = (float*)d_out;

    char* ws = (char*)d_ws;
    int*   tk_idx = (int*)ws;                    // 1 MB
    float* tk_val = (float*)(ws + (1u << 20));   // 1 MB
    char*  Bp     = ws + (2u << 20);             // 1 MB f16 B fragments

    cvt_bfrag<<<256, 256, 0, stream>>>(cb1, cb2, Bp);
    dim3 g1(NTOK / TMB, 2);
    score_topk_fused<<<g1, 512, 0, stream>>>(query, cb1, cb2, Bp, tk_idx, tk_val);
    gather_kernel<<<NTOK / 4, 256, 0, stream>>>(values, tk_idx, tk_val, out);
}

// Round 13
// 309.857 us; speedup vs baseline: 1.7816x; 1.7816x over previous
//
#include <hip/hip_runtime.h>
#include <hip/hip_bf16.h>
#include <math.h>

#define NTOK 16384
#define DDIM 1024
#define HALF 512
#define SUB  512
#define KDIM 512
#define TOPK 8
#define NCAND 16
#define VDIM 128
#define TMB 32          // tokens per block (score kernel)
#define GATE 1.2e-3f

typedef __attribute__((ext_vector_type(8))) _Float16 f16x8;
typedef __attribute__((ext_vector_type(4))) float f32x4;

static __device__ __forceinline__ int pk2(float a, float b) {
    _Float16 ha = (_Float16)a, hb = (_Float16)b;
    return (int)__builtin_bit_cast(unsigned short, ha)
         | ((int)__builtin_bit_cast(unsigned short, hb) << 16);
}

// ---------------------------------------------------------------------------
// Kernel 0: codebooks -> single-f16 MFMA-B fragments.
//   slice = hf*4 + cq (cq = 128-cand wave slice); step s = kstep*8 + nt.
//   frag elem: n = cq*128 + nt*16 + (lane&15), k = kstep*32 + (lane>>4)*8 + j.
// ---------------------------------------------------------------------------
__global__ __launch_bounds__(256)
void cvt_bfrag(const float* __restrict__ cb1, const float* __restrict__ cb2,
               char* __restrict__ Bp)
{
    int fid   = blockIdx.x * 256 + threadIdx.x;   // 0..65535
    int lane  = fid & 63;
    int s     = (fid >> 6) & 127;
    int slice = fid >> 13;
    int nt = s & 7, kstep = s >> 3;
    int cq = slice & 3, hf = slice >> 2;
    const float* cb = hf ? cb2 : cb1;
    int n = cq * 128 + nt * 16 + (lane & 15);
    int k = kstep * 32 + (lane >> 4) * 8;
    const float* src = cb + (size_t)n * KDIM + k;
    float4 f0 = *(const float4*)src;
    float4 f1 = *(const float4*)(src + 4);
    int4 v;
    v.x = pk2(f0.x, f0.y); v.y = pk2(f0.z, f0.w);
    v.z = pk2(f1.x, f1.y); v.w = pk2(f1.z, f1.w);
    *(int4*)(Bp + (size_t)fid * 16) = v;
}

// ---------------------------------------------------------------------------
// Slow path (outlined, noinline): fp64-exact top-8 for ambiguous tokens.
// Isolates its ~80-reg transient from the main kernel's allocation.
// ---------------------------------------------------------------------------
__device__ __attribute__((noinline)) void slowpath_fn(
    const float* sS, int t, int tok, int hf, int lane,
    const float* query, const float* cbf,
    int* tk_idx, float* tk_val)
{
    const int qoff = hf * HALF;
    const int hsh  = ((t >> 2) & 3) << 3;
    float sv[8];
    #pragma unroll
    for (int j = 0; j < 8; j++) sv[j] = sS[t * SUB + ((lane + 64 * j) ^ hsh)];

    int cand[NCAND];
    #pragma unroll
    for (int r = 0; r < NCAND; r++) {
        float bv = sv[0]; int bj = 0;
        #pragma unroll
        for (int j = 1; j < 8; j++) if (sv[j] > bv) { bv = sv[j]; bj = j; }
        int bidx = lane + 64 * bj;
        #pragma unroll
        for (int off = 32; off > 0; off >>= 1) {
            float ov = __shfl_xor(bv, off);
            int   oi = __shfl_xor(bidx, off);
            if (ov > bv || (ov == bv && oi < bidx)) { bv = ov; bidx = oi; }
        }
        cand[r] = bidx;
        int jj = bidx >> 6;
        if ((bidx & 63) == lane) {
            #pragma unroll
            for (int j = 0; j < 8; j++) if (j == jj) sv[j] = -INFINITY;
        }
    }
    double qd[8];
    #pragma unroll
    for (int j = 0; j < 8; j++)
        qd[j] = (double)query[(size_t)tok * DDIM + qoff + lane + 64 * j];
    double rv[NCAND];
    #pragma unroll
    for (int r = 0; r < NCAND; r++) {
        const float* crow = &cbf[(size_t)cand[r] * KDIM];
        double a = 0.0;
        #pragma unroll
        for (int j = 0; j < 8; j++)
            a = fma(qd[j], (double)crow[lane + 64 * j], a);
        #pragma unroll
        for (int off = 32; off > 0; off >>= 1)
            a += __shfl_xor(a, off);
        rv[r] = a;
    }
    if (lane == 0) {
        #pragma unroll
        for (int r = 0; r < NCAND; r++) {
            int rk = 0;
            #pragma unroll
            for (int mm = 0; mm < NCAND; mm++)
                if (rv[mm] > rv[r] || (rv[mm] == rv[r] && cand[mm] < cand[r])) rk++;
            if (rk < TOPK) {
                tk_idx[((size_t)tok * 2 + hf) * TOPK + rk] = cand[r];
                tk_val[((size_t)tok * 2 + hf) * TOPK + rk] = (float)rv[r];
            }
        }
    }
}

// ---------------------------------------------------------------------------
// Kernel 1: fused score+topk. 256 threads (4 waves), 32 tokens, one half.
//   Wave = 128-cand slice (8 nt). SINGLE-term f16: s = q_f16 * c_f16
//   (coarse err ~1.6e-4; gate 1.2e-3 + fp64 slow path keeps top-8 set exact).
//   A: 32 tok x 512 k f16 fragments in 32 KB LDS (one staging pass).
//   B: global->reg 8-slot ring; 2 MFMAs per 1 KB load.
//   Phase 2: R6-verbatim inline ballot-bisect; slow path outlined.
// ---------------------------------------------------------------------------
__global__ __launch_bounds__(256, 3)
void score_topk_fused(const float* __restrict__ query,
                      const float* __restrict__ cb1f,
                      const float* __restrict__ cb2f,
                      const char* __restrict__ Bp,
                      int*   __restrict__ tk_idx,
                      float* __restrict__ tk_val)
{
    __shared__ char smem[32768];
    // GEMM: A frags [kc(16)][tt(2)][lane*16B]; phase 2: sS[16][512] overlays
    float* sS = (float*)smem;

    const int tid  = threadIdx.x;
    const int hf   = blockIdx.y;
    const int tok0 = blockIdx.x * TMB;
    const float* __restrict__ cbf = hf ? cb2f : cb1f;
    const int qoff = hf * HALF;

    const int lane = tid & 63;
    const int wid  = tid >> 6;          // 0..3 = 128-cand slice
    const int l15  = lane & 15;
    const int lh   = lane >> 4;

    // ---- stage A: 32 tok x 512 k fp32 -> f16 fragments (one pass) ----
    {
        const int tok = tid >> 3;        // 0..31
        const int seg = tid & 7;         // 64-k segment
        const int tt  = tok >> 4;
        const int r15 = tok & 15;
        const float* src = query + (size_t)(tok0 + tok) * DDIM + qoff + seg * 64;
        #pragma unroll
        for (int sub = 0; sub < 2; sub++) {
            const int kc = seg * 2 + sub;
            #pragma unroll
            for (int lh2 = 0; lh2 < 4; lh2++) {
                float4 f0 = *(const float4*)(src + sub * 32 + lh2 * 8);
                float4 f1 = *(const float4*)(src + sub * 32 + lh2 * 8 + 4);
                int4 v;
                v.x = pk2(f0.x, f0.y); v.y = pk2(f0.z, f0.w);
                v.z = pk2(f1.x, f1.y); v.w = pk2(f1.z, f1.w);
                *(int4*)(smem + kc * 2048 + tt * 1024 + (lh2 * 16 + r15) * 16) = v;
            }
        }
    }
    __syncthreads();

    // ---- B stream: 128 steps, 8-slot ring, 2 MFMAs per load ----
    const char* bp = Bp + (size_t)(hf * 4 + wid) * 131072 + lane * 16;
    int4 ring[8];
    #pragma unroll
    for (int j = 0; j < 8; j++) ring[j] = *(const int4*)(bp + j * 1024);

    f32x4 acc0[8], acc1[8];
    #pragma unroll
    for (int nt = 0; nt < 8; nt++) {
        acc0[nt] = (f32x4){0.f, 0.f, 0.f, 0.f};
        acc1[nt] = (f32x4){0.f, 0.f, 0.f, 0.f};
    }

    for (int kc = 0; kc < 16; kc++) {
        const char* abase = smem + kc * 2048;
        f16x8 a0 = *(const f16x8*)(abase + lane * 16);
        f16x8 a1 = *(const f16x8*)(abase + 1024 + lane * 16);
        #pragma unroll
        for (int nt = 0; nt < 8; nt++) {
            f16x8 b = __builtin_bit_cast(f16x8, ring[nt]);
            ring[nt] = *(const int4*)(bp + ((kc * 8 + nt + 8) & 127) * 1024);
            acc0[nt] = __builtin_amdgcn_mfma_f32_16x16x32_f16(a0, b, acc0[nt], 0, 0, 0);
            acc1[nt] = __builtin_amdgcn_mfma_f32_16x16x32_f16(a1, b, acc1[nt], 0, 0, 0);
        }
    }
    __syncthreads();   // all A reads done; sS may overwrite

    // ================= phase 2: round 0 (tokens 0-15, acc0) =================
    #pragma unroll
    for (int nt = 0; nt < 8; nt++)
        #pragma unroll
        for (int r = 0; r < 4; r++) {
            int t = lh * 4 + r;
            int c = wid * 128 + nt * 16 + l15;
            sS[t * SUB + (c ^ (lh << 3))] = acc0[nt][r];
        }
    __syncthreads();

    for (int v = 0; v < 4; v++) {
        const int t   = wid * 4 + v;
        const int tok = tok0 + t;
        const int hsh = ((t >> 2) & 3) << 3;

        float sv[8];
        #pragma unroll
        for (int j = 0; j < 8; j++) sv[j] = sS[t * SUB + ((lane + 64 * j) ^ hsh)];

        float m = sv[0];
        #pragma unroll
        for (int j = 1; j < 8; j++) m = fmaxf(m, sv[j]);
        #pragma unroll
        for (int off = 32; off > 0; off >>= 1) m = fmaxf(m, __shfl_xor(m, off));

        auto wave_cnt = [&](float tau) -> int {
            int c = 0;
            #pragma unroll
            for (int j = 0; j < 8; j++)
                c += __popcll(__ballot(sv[j] > tau));
            return c;
        };

        float lo = m - 0.5f, hi = m;
        while (wave_cnt(lo) < 9) lo -= 0.5f;
        for (int it = 0; it < 14; it++) {
            float mid = 0.5f * (lo + hi);
            if (wave_cnt(mid) >= 9) lo = mid; else hi = mid;
        }
        int ch8 = wave_cnt(hi);

        float v8 = 1e30f, v9 = -1e30f;
        #pragma unroll
        for (int j = 0; j < 8; j++) {
            bool sel = sv[j] > hi;
            v8 = sel ? fminf(v8, sv[j]) : v8;
            v9 = sel ? v9 : fmaxf(v9, sv[j]);
        }
        #pragma unroll
        for (int off = 32; off > 0; off >>= 1) {
            v8 = fminf(v8, __shfl_xor(v8, off));
            v9 = fmaxf(v9, __shfl_xor(v9, off));
        }

        if (ch8 == 8 && (v8 - v9) > GATE) {
            int base = 0;
            #pragma unroll
            for (int j = 0; j < 8; j++) {
                unsigned long long mk = __ballot(sv[j] > hi);
                if (sv[j] > hi) {
                    int pos = base + __popcll(mk & ((1ULL << lane) - 1ULL));
                    tk_idx[((size_t)tok * 2 + hf) * TOPK + pos] = lane + 64 * j;
                    tk_val[((size_t)tok * 2 + hf) * TOPK + pos] = sv[j];
                }
                base += __popcll(mk);
            }
        } else {
            slowpath_fn(sS, t, tok, hf, lane, query, cbf, tk_idx, tk_val);
        }
    }
    __syncthreads();

    // ================= phase 2: round 1 (tokens 16-31, acc1) ================
    #pragma unroll
    for (int nt = 0; nt < 8; nt++)
        #pragma unroll
        for (int r = 0; r < 4; r++) {
            int t = lh * 4 + r;
            int c = wid * 128 + nt * 16 + l15;
            sS[t * SUB + (c ^ (lh << 3))] = acc1[nt][r];
        }
    __syncthreads();

    for (int v = 0; v < 4; v++) {
        const int t   = wid * 4 + v;
        const int tok = tok0 + 16 + t;
        const int hsh = ((t >> 2) & 3) << 3;

        float sv[8];
        #pragma unroll
        for (int j = 0; j < 8; j++) sv[j] = sS[t * SUB + ((lane + 64 * j) ^ hsh)];

        float m = sv[0];
        #pragma unroll
        for (int j = 1; j < 8; j++) m = fmaxf(m, sv[j]);
        #pragma unroll
        for (int off = 32; off > 0; off >>= 1) m = fmaxf(m, __shfl_xor(m, off));

        auto wave_cnt = [&](float tau) -> int {
            int c = 0;
            #pragma unroll
            for (int j = 0; j < 8; j++)
                c += __popcll(__ballot(sv[j] > tau));
            return c;
        };

        float lo = m - 0.5f, hi = m;
        while (wave_cnt(lo) < 9) lo -= 0.5f;
        for (int it = 0; it < 14; it++) {
            float mid = 0.5f * (lo + hi);
            if (wave_cnt(mid) >= 9) lo = mid; else hi = mid;
        }
        int ch8 = wave_cnt(hi);

        float v8 = 1e30f, v9 = -1e30f;
        #pragma unroll
        for (int j = 0; j < 8; j++) {
            bool sel = sv[j] > hi;
            v8 = sel ? fminf(v8, sv[j]) : v8;
            v9 = sel ? v9 : fmaxf(v9, sv[j]);
        }
        #pragma unroll
        for (int off = 32; off > 0; off >>= 1) {
            v8 = fminf(v8, __shfl_xor(v8, off));
            v9 = fmaxf(v9, __shfl_xor(v9, off));
        }

        if (ch8 == 8 && (v8 - v9) > GATE) {
            int base = 0;
            #pragma unroll
            for (int j = 0; j < 8; j++) {
                unsigned long long mk = __ballot(sv[j] > hi);
                if (sv[j] > hi) {
                    int pos = base + __popcll(mk & ((1ULL << lane) - 1ULL));
                    tk_idx[((size_t)tok * 2 + hf) * TOPK + pos] = lane + 64 * j;
                    tk_val[((size_t)tok * 2 + hf) * TOPK + pos] = sv[j];
                }
                base += __popcll(mk);
            }
        } else {
            slowpath_fn(sS, t, tok, hf, lane, query, cbf, tk_idx, tk_val);
        }
    }
}

// ---------------------------------------------------------------------------
// Kernel 2: one wave per token. softmax(8)x2 -> 64 weighted value rows.
// (R6-proven float2 version, ~51 us)
// ---------------------------------------------------------------------------
__global__ __launch_bounds__(256)
void gather_kernel(const float* __restrict__ values,
                   const int*   __restrict__ tk_idx,
                   const float* __restrict__ tk_val,
                   float* __restrict__ out)
{
    const int tid  = threadIdx.x;
    const int lane = tid & 63;
    const int tok  = blockIdx.x * 4 + (tid >> 6);

    const int b1 = (tok * 2 + 0) * TOPK;
    const int b2 = (tok * 2 + 1) * TOPK;

    float v1[8], v2[8]; int i1[8], i2[8];
    #pragma unroll
    for (int j = 0; j < 8; j++) {
        i1[j] = tk_idx[b1 + j]; v1[j] = tk_val[b1 + j];
        i2[j] = tk_idx[b2 + j]; v2[j] = tk_val[b2 + j];
    }

    float m1 = v1[0], m2 = v2[0];
    #pragma unroll
    for (int j = 1; j < 8; j++) { m1 = fmaxf(m1, v1[j]); m2 = fmaxf(m2, v2[j]); }

    float w1[8], w2[8], s1 = 0.f, s2 = 0.f;
    #pragma unroll
    for (int j = 0; j < 8; j++) {
        w1[j] = expf(v1[j] - m1); s1 += w1[j];
        w2[j] = expf(v2[j] - m2); s2 += w2[j];
    }
    const float inv1 = 1.f / s1, inv2 = 1.f / s2;
    #pragma unroll
    for (int j = 0; j < 8; j++) { w1[j] *= inv1; w2[j] *= inv2; }

    float2 accA = make_float2(0.f, 0.f), accB = make_float2(0.f, 0.f);
    #pragma unroll
    for (int i = 0; i < 8; i++) {
        const int rb = i1[i] * SUB;
        const float wi = w1[i];
        #pragma unroll
        for (int j = 0; j < 8; j += 2) {
            const float wa = wi * w2[j];
            const float wb = wi * w2[j + 1];
            const float* __restrict__ ra  = values + (size_t)(rb + i2[j])     * VDIM;
            const float* __restrict__ rbp = values + (size_t)(rb + i2[j + 1]) * VDIM;
            float2 ta = *(const float2*)&ra[lane * 2];
            float2 tb = *(const float2*)&rbp[lane * 2];
            accA.x = fmaf(wa, ta.x, accA.x);
            accA.y = fmaf(wa, ta.y, accA.y);
            accB.x = fmaf(wb, tb.x, accB.x);
            accB.y = fmaf(wb, tb.y, accB.y);
        }
    }
    float2 acc = make_float2(accA.x + accB.x, accA.y + accB.y);
    *(float2*)&out[(size_t)tok * VDIM + lane * 2] = acc;
}

extern "C" void kernel_launch(void* const* d_in, const int* in_sizes, int n_in,
                              void* d_out, int out_size, void* d_ws, size_t ws_size,
                              hipStream_t stream) {
    const float* query  = (const float*)d_in[0];
    const float* cb1    = (const float*)d_in[1];
    const float* cb2    = (const float*)d_in[2];
    const float* values = (const float*)d_in[3];
    float* out = (float*)d_out;

    char* ws = (char*)d_ws;
    int*   tk_idx = (int*)ws;                    // 1 MB
    float* tk_val = (float*)(ws + (1u << 20));   // 1 MB
    char*  Bp     = ws + (2u << 20);             // 1 MB f16 B fragments

    cvt_bfrag<<<256, 256, 0, stream>>>(cb1, cb2, Bp);
    dim3 g1(NTOK / TMB, 2);
    score_topk_fused<<<g1, 256, 0, stream>>>(query, cb1, cb2, Bp, tk_idx, tk_val);
    gather_kernel<<<NTOK / 4, 256, 0, stream>>>(values, tk_idx, tk_val, out);
}

// Round 14
// 232.955 us; speedup vs baseline: 2.3698x; 1.3301x over previous
//
#include <hip/hip_runtime.h>
#include <hip/hip_bf16.h>
#include <math.h>

#define NTOK 16384
#define DDIM 1024
#define HALF 512
#define SUB  512
#define KDIM 512
#define TOPK 8
#define NCAND 16
#define VDIM 128
#define TMB 32
#define GATE 1.2e-3f

typedef __attribute__((ext_vector_type(8))) _Float16 f16x8;
typedef __attribute__((ext_vector_type(4))) float f32x4;

static __device__ __forceinline__ int pk2(float a, float b) {
    _Float16 ha = (_Float16)a, hb = (_Float16)b;
    return (int)__builtin_bit_cast(unsigned short, ha)
         | ((int)__builtin_bit_cast(unsigned short, hb) << 16);
}

// ---------------------------------------------------------------------------
// Kernel 0: codebooks -> single-f16 MFMA-B fragments (R13-proven).
//   slice = hf*4 + cq; step s = kstep*8 + nt.
//   frag elem: n = cq*128 + nt*16 + (lane&15), k = kstep*32 + (lane>>4)*8 + j.
// ---------------------------------------------------------------------------
__global__ __launch_bounds__(256)
void cvt_bfrag(const float* __restrict__ cb1, const float* __restrict__ cb2,
               char* __restrict__ Bp)
{
    int fid   = blockIdx.x * 256 + threadIdx.x;   // 0..65535
    int lane  = fid & 63;
    int s     = (fid >> 6) & 127;
    int slice = fid >> 13;
    int nt = s & 7, kstep = s >> 3;
    int cq = slice & 3, hf = slice >> 2;
    const float* cb = hf ? cb2 : cb1;
    int n = cq * 128 + nt * 16 + (lane & 15);
    int k = kstep * 32 + (lane >> 4) * 8;
    const float* src = cb + (size_t)n * KDIM + k;
    float4 f0 = *(const float4*)src;
    float4 f1 = *(const float4*)(src + 4);
    int4 v;
    v.x = pk2(f0.x, f0.y); v.y = pk2(f0.z, f0.w);
    v.z = pk2(f1.x, f1.y); v.w = pk2(f1.z, f1.w);
    *(int4*)(Bp + (size_t)fid * 16) = v;
}

// ---------------------------------------------------------------------------
// Kernel 1: pure score GEMM (R13's GEMM half; no phase 2 -> no scratch risk).
//   256 thr (4 waves), 32 tokens, one half; wave = 128-cand slice.
//   A: 32 tok x 512 k f16 fragments in 32 KB LDS. B: 8-slot global ring.
//   Single-term f16: coarse err ~1.3e-4; exactness restored downstream.
// ---------------------------------------------------------------------------
__global__ __launch_bounds__(256, 3)
void score_gemm(const float* __restrict__ query,
                const char* __restrict__ Bp,
                float* __restrict__ scores)
{
    __shared__ char smem[32768];   // A frags [kc(16)][tt(2)][lane*16B]

    const int tid  = threadIdx.x;
    const int hf   = blockIdx.y;
    const int tok0 = blockIdx.x * TMB;
    const int qoff = hf * HALF;

    const int lane = tid & 63;
    const int wid  = tid >> 6;
    const int l15  = lane & 15;
    const int lh   = lane >> 4;

    // ---- stage A (R13-verbatim, numerics validated) ----
    {
        const int tok = tid >> 3;
        const int seg = tid & 7;
        const int tt  = tok >> 4;
        const int r15 = tok & 15;
        const float* src = query + (size_t)(tok0 + tok) * DDIM + qoff + seg * 64;
        #pragma unroll
        for (int sub = 0; sub < 2; sub++) {
            const int kc = seg * 2 + sub;
            #pragma unroll
            for (int lh2 = 0; lh2 < 4; lh2++) {
                float4 f0 = *(const float4*)(src + sub * 32 + lh2 * 8);
                float4 f1 = *(const float4*)(src + sub * 32 + lh2 * 8 + 4);
                int4 v;
                v.x = pk2(f0.x, f0.y); v.y = pk2(f0.z, f0.w);
                v.z = pk2(f1.x, f1.y); v.w = pk2(f1.z, f1.w);
                *(int4*)(smem + kc * 2048 + tt * 1024 + (lh2 * 16 + r15) * 16) = v;
            }
        }
    }
    __syncthreads();

    const char* bp = Bp + (size_t)(hf * 4 + wid) * 131072 + lane * 16;
    int4 ring[8];
    #pragma unroll
    for (int j = 0; j < 8; j++) ring[j] = *(const int4*)(bp + j * 1024);

    f32x4 acc0[8], acc1[8];
    #pragma unroll
    for (int nt = 0; nt < 8; nt++) {
        acc0[nt] = (f32x4){0.f, 0.f, 0.f, 0.f};
        acc1[nt] = (f32x4){0.f, 0.f, 0.f, 0.f};
    }

    for (int kc = 0; kc < 16; kc++) {
        const char* abase = smem + kc * 2048;
        f16x8 a0 = *(const f16x8*)(abase + lane * 16);
        f16x8 a1 = *(const f16x8*)(abase + 1024 + lane * 16);
        #pragma unroll
        for (int nt = 0; nt < 8; nt++) {
            f16x8 b = __builtin_bit_cast(f16x8, ring[nt]);
            ring[nt] = *(const int4*)(bp + ((kc * 8 + nt + 8) & 127) * 1024);
            acc0[nt] = __builtin_amdgcn_mfma_f32_16x16x32_f16(a0, b, acc0[nt], 0, 0, 0);
            acc1[nt] = __builtin_amdgcn_mfma_f32_16x16x32_f16(a1, b, acc1[nt], 0, 0, 0);
        }
    }

    // ---- C-write: row=(lane>>4)*4+r (token), col=lane&15 (cand) ----
    #pragma unroll
    for (int nt = 0; nt < 8; nt++)
        #pragma unroll
        for (int r = 0; r < 4; r++) {
            const int c = hf * 512 + wid * 128 + nt * 16 + l15;
            scores[((size_t)(tok0 + lh * 4 + r) << 10) + c]      = acc0[nt][r];
            scores[((size_t)(tok0 + 16 + lh * 4 + r) << 10) + c] = acc1[nt][r];
        }
}

// ---------------------------------------------------------------------------
// Kernel 2: fast top-k. One wave per (tok,half). NO fp64 code -> tiny VGPR,
// high occupancy. Gated tokens get flags=1 for the slow kernel.
// ---------------------------------------------------------------------------
__global__ __launch_bounds__(256)
void topk_fast(const float* __restrict__ scores,
               int*   __restrict__ tk_idx,
               float* __restrict__ tk_val,
               int*   __restrict__ flags)
{
    const int tid  = threadIdx.x;
    const int lane = tid & 63;
    const int gid  = blockIdx.x * 4 + (tid >> 6);   // tok*2 + hf

    float sv[8];
    #pragma unroll
    for (int j = 0; j < 8; j++)
        sv[j] = scores[((size_t)gid << 9) + lane + 64 * j];

    float m = sv[0];
    #pragma unroll
    for (int j = 1; j < 8; j++) m = fmaxf(m, sv[j]);
    #pragma unroll
    for (int off = 32; off > 0; off >>= 1) m = fmaxf(m, __shfl_xor(m, off));

    auto wave_cnt = [&](float tau) -> int {
        int c = 0;
        #pragma unroll
        for (int j = 0; j < 8; j++)
            c += __popcll(__ballot(sv[j] > tau));
        return c;
    };

    float lo = m - 0.5f, hi = m;
    while (wave_cnt(lo) < 9) lo -= 0.5f;
    for (int it = 0; it < 14; it++) {
        float mid = 0.5f * (lo + hi);
        if (wave_cnt(mid) >= 9) lo = mid; else hi = mid;
    }
    int ch8 = wave_cnt(hi);

    float v8 = 1e30f, v9 = -1e30f;
    #pragma unroll
    for (int j = 0; j < 8; j++) {
        bool sel = sv[j] > hi;
        v8 = sel ? fminf(v8, sv[j]) : v8;
        v9 = sel ? v9 : fmaxf(v9, sv[j]);
    }
    #pragma unroll
    for (int off = 32; off > 0; off >>= 1) {
        v8 = fminf(v8, __shfl_xor(v8, off));
        v9 = fmaxf(v9, __shfl_xor(v9, off));
    }

    const bool fast = (ch8 == 8) && ((v8 - v9) > GATE);
    if (fast) {
        int base = 0;
        #pragma unroll
        for (int j = 0; j < 8; j++) {
            unsigned long long mk = __ballot(sv[j] > hi);
            if (sv[j] > hi) {
                int pos = base + __popcll(mk & ((1ULL << lane) - 1ULL));
                tk_idx[(size_t)gid * TOPK + pos] = lane + 64 * j;
                tk_val[(size_t)gid * TOPK + pos] = sv[j];
            }
            base += __popcll(mk);
        }
    }
    if (lane == 0) flags[gid] = fast ? 0 : 1;
}

// ---------------------------------------------------------------------------
// Kernel 3: slow top-k (fp64-exact) for flagged tokens only (~6%). The
// fat-register fp64 path lives alone here; 94% of waves exit immediately.
// ---------------------------------------------------------------------------
__global__ __launch_bounds__(256)
void topk_slow(const float* __restrict__ scores,
               const float* __restrict__ query,
               const float* __restrict__ cb1f,
               const float* __restrict__ cb2f,
               int*   __restrict__ tk_idx,
               float* __restrict__ tk_val,
               const int* __restrict__ flags)
{
    const int tid  = threadIdx.x;
    const int lane = tid & 63;
    const int gid  = blockIdx.x * 4 + (tid >> 6);   // tok*2 + hf
    if (flags[gid] == 0) return;                    // wave-uniform

    const int tok = gid >> 1;
    const int hf  = gid & 1;
    const float* __restrict__ cbf = hf ? cb2f : cb1f;
    const int qoff = hf * HALF;

    float sv[8];
    #pragma unroll
    for (int j = 0; j < 8; j++)
        sv[j] = scores[((size_t)gid << 9) + lane + 64 * j];

    // coarse top-16 via wave-argmax (tie -> lower index)
    int cand[NCAND];
    #pragma unroll
    for (int r = 0; r < NCAND; r++) {
        float bv = sv[0]; int bj = 0;
        #pragma unroll
        for (int j = 1; j < 8; j++) if (sv[j] > bv) { bv = sv[j]; bj = j; }
        int bidx = lane + 64 * bj;
        #pragma unroll
        for (int off = 32; off > 0; off >>= 1) {
            float ov = __shfl_xor(bv, off);
            int   oi = __shfl_xor(bidx, off);
            if (ov > bv || (ov == bv && oi < bidx)) { bv = ov; bidx = oi; }
        }
        cand[r] = bidx;
        int jj = bidx >> 6;
        if ((bidx & 63) == lane) {
            #pragma unroll
            for (int j = 0; j < 8; j++) if (j == jj) sv[j] = -INFINITY;
        }
    }

    // fp64 rescore -> exact ordering + exact logits
    double qd[8];
    #pragma unroll
    for (int j = 0; j < 8; j++)
        qd[j] = (double)query[(size_t)tok * DDIM + qoff + lane + 64 * j];
    double rv[NCAND];
    #pragma unroll
    for (int r = 0; r < NCAND; r++) {
        const float* __restrict__ crow = &cbf[(size_t)cand[r] * KDIM];
        double a = 0.0;
        #pragma unroll
        for (int j = 0; j < 8; j++)
            a = fma(qd[j], (double)crow[lane + 64 * j], a);
        #pragma unroll
        for (int off = 32; off > 0; off >>= 1)
            a += __shfl_xor(a, off);
        rv[r] = a;
    }
    if (lane == 0) {
        #pragma unroll
        for (int r = 0; r < NCAND; r++) {
            int rk = 0;
            #pragma unroll
            for (int mm = 0; mm < NCAND; mm++)
                if (rv[mm] > rv[r] || (rv[mm] == rv[r] && cand[mm] < cand[r])) rk++;
            if (rk < TOPK) {
                tk_idx[(size_t)gid * TOPK + rk] = cand[r];
                tk_val[(size_t)gid * TOPK + rk] = (float)rv[r];
            }
        }
    }
}

// ---------------------------------------------------------------------------
// Kernel 4: gather (R6-proven float2 version, ~51 us)
// ---------------------------------------------------------------------------
__global__ __launch_bounds__(256)
void gather_kernel(const float* __restrict__ values,
                   const int*   __restrict__ tk_idx,
                   const float* __restrict__ tk_val,
                   float* __restrict__ out)
{
    const int tid  = threadIdx.x;
    const int lane = tid & 63;
    const int tok  = blockIdx.x * 4 + (tid >> 6);

    const int b1 = (tok * 2 + 0) * TOPK;
    const int b2 = (tok * 2 + 1) * TOPK;

    float v1[8], v2[8]; int i1[8], i2[8];
    #pragma unroll
    for (int j = 0; j < 8; j++) {
        i1[j] = tk_idx[b1 + j]; v1[j] = tk_val[b1 + j];
        i2[j] = tk_idx[b2 + j]; v2[j] = tk_val[b2 + j];
    }

    float m1 = v1[0], m2 = v2[0];
    #pragma unroll
    for (int j = 1; j < 8; j++) { m1 = fmaxf(m1, v1[j]); m2 = fmaxf(m2, v2[j]); }

    float w1[8], w2[8], s1 = 0.f, s2 = 0.f;
    #pragma unroll
    for (int j = 0; j < 8; j++) {
        w1[j] = expf(v1[j] - m1); s1 += w1[j];
        w2[j] = expf(v2[j] - m2); s2 += w2[j];
    }
    const float inv1 = 1.f / s1, inv2 = 1.f / s2;
    #pragma unroll
    for (int j = 0; j < 8; j++) { w1[j] *= inv1; w2[j] *= inv2; }

    float2 accA = make_float2(0.f, 0.f), accB = make_float2(0.f, 0.f);
    #pragma unroll
    for (int i = 0; i < 8; i++) {
        const int rb = i1[i] * SUB;
        const float wi = w1[i];
        #pragma unroll
        for (int j = 0; j < 8; j += 2) {
            const float wa = wi * w2[j];
            const float wb = wi * w2[j + 1];
            const float* __restrict__ ra  = values + (size_t)(rb + i2[j])     * VDIM;
            const float* __restrict__ rbp = values + (size_t)(rb + i2[j + 1]) * VDIM;
            float2 ta = *(const float2*)&ra[lane * 2];
            float2 tb = *(const float2*)&rbp[lane * 2];
            accA.x = fmaf(wa, ta.x, accA.x);
            accA.y = fmaf(wa, ta.y, accA.y);
            accB.x = fmaf(wb, tb.x, accB.x);
            accB.y = fmaf(wb, tb.y, accB.y);
        }
    }
    float2 acc = make_float2(accA.x + accB.x, accA.y + accB.y);
    *(float2*)&out[(size_t)tok * VDIM + lane * 2] = acc;
}

extern "C" void kernel_launch(void* const* d_in, const int* in_sizes, int n_in,
                              void* d_out, int out_size, void* d_ws, size_t ws_size,
                              hipStream_t stream) {
    const float* query  = (const float*)d_in[0];
    const float* cb1    = (const float*)d_in[1];
    const float* cb2    = (const float*)d_in[2];
    const float* values = (const float*)d_in[3];
    float* out = (float*)d_out;

    char* ws = (char*)d_ws;
    int*   tk_idx = (int*)ws;                          // 1 MB
    float* tk_val = (float*)(ws + (1u << 20));         // 1 MB
    char*  Bp     = ws + (2u << 20);                   // 1 MB f16 B fragments
    int*   flags  = (int*)(ws + (3u << 20));           // 128 KB
    float* scores = (float*)(ws + (4u << 20));         // 64 MB [16384][1024]

    cvt_bfrag<<<256, 256, 0, stream>>>(cb1, cb2, Bp);
    dim3 g1(NTOK / TMB, 2);
    score_gemm<<<g1, 256, 0, stream>>>(query, Bp, scores);
    topk_fast<<<NTOK * 2 / 4, 256, 0, stream>>>(scores, tk_idx, tk_val, flags);
    topk_slow<<<NTOK * 2 / 4, 256, 0, stream>>>(scores, query, cb1, cb2,
                                                tk_idx, tk_val, flags);
    gather_kernel<<<NTOK / 4, 256, 0, stream>>>(values, tk_idx, tk_val, out);
}